// Round 3
// baseline (529.666 us; speedup 1.0000x reference)
//
#include <hip/hip_runtime.h>
#include <hip/hip_bf16.h>

// GCN 2-layer on MI355X — global-atomic-free CSR build + register-acc aggregation.
// R5: global atomicAdd walled ~24 ops/ns device-wide -> no global atomics.
// R6: bucketed LDS-atomic aggregation FAILED (no TLP + in-order LDS pipe).
// R7/R8: hist->scan->part->sort2 CSR + wave-per-node register-acc agg.
// R9/R10: MFMA gemm spill-bound at 98us (frag cache > VGPR budget).
// R11: LDS-free MFMA gemm -> gemm off top-5; agg1 89us @ 3.36 TB/s.
// R12: wide-gather agg1 REGRESSED: VMEM index loads entered the gather chain.
// R13: 512-node buckets: -15us on the partition pipeline.
// R14: deeper gather pipeline neutral -> agg1 at the L2-miss path wall.
// R15: harness feeds f32 -> LDS-free MFMA gemm via bf16 hi/lo split. -26us.
// R16: quartered hbq[q][N][16] (3.2MB < 4MB/XCD L2), quarter-major sweep.
//      FETCH 292->128MB (residency PROVEN) but dur 88->167us: inner loop
//      had only 4-8 gathers in flight (vs 16 before) + node-serial passes
//      -> latency-bound at L2-hit latency.
// R17: restore MLP inside the quartered sweep. Each 16-lane group owns a
//      DIFFERENT node (wave = 4 concurrent nodes x 4 batches = 16 nodes);
//      per chunk: 16 contiguous index loads/group, 16 in-group shuffles,
//      16 gather instrs in flight (4 rows x 32B each = 128B, same MLP as
//      the 88us kernel). Lane (g,r) accumulates feature q*16+r of its
//      group's node directly -> no cross-lane reduce, no deposit trick,
//      acc[4][4] fully static. start[] preloaded+shuffled, q-invariant.

typedef short s8_t __attribute__((ext_vector_type(8)));
typedef float f4_t __attribute__((ext_vector_type(4)));

__device__ __forceinline__ float bf2f(unsigned short u) {
    union { unsigned int u; float f; } c; c.u = ((unsigned int)u) << 16; return c.f;
}
__device__ __forceinline__ unsigned short f2bf(float f) {
    union { float f; unsigned int u; } c; c.f = f;
    unsigned int u = c.u;
    unsigned int r = (u + 0x7fffu + ((u >> 16) & 1u)) >> 16;  // round-nearest-even
    return (unsigned short)r;
}
__device__ __forceinline__ float loadF(const void* p, int i, int isbf) {
    return isbf ? bf2f(((const unsigned short*)p)[i]) : ((const float*)p)[i];
}
__device__ __forceinline__ int edgeIdx(const void* e, long long i, int is64) {
    return is64 ? (int)((const long long*)e)[i] : ((const int*)e)[i];
}

// flags[0] = edge indices are int64; flags[1] = float tensors are bf16
__global__ void k_detect(const void* e, const void* x, int* flags) {
    int lane = threadIdx.x;  // blockDim = 64
    unsigned int ew = ((const unsigned int*)e)[2 * lane + 1];
    unsigned long long nz = __ballot(ew != 0);
    unsigned int xw = ((const unsigned int*)x)[lane];
    unsigned int low = xw & 0xffffu;
    unsigned int e8 = (low >> 7) & 0xffu;
    bool plaus = (low == 0u) || (e8 >= 110u && e8 <= 135u);
    unsigned long long pl = __ballot(plaus);
    if (lane == 0) {
        flags[0] = (nz == 0ull) ? 1 : 0;
        flags[1] = (__popcll(pl) > 32) ? 1 : 0;
    }
}

// Merged weight prep. bf16 mode: wT[n][k] = W1[k][n].
// f32 mode: transposed bf16 hi/lo pair wTh + wTl ~= W1^T (rne split).
__global__ void k_prep_all(const void* W1, unsigned short* __restrict__ wT,
                           unsigned short* __restrict__ wTh,
                           unsigned short* __restrict__ wTl, const int* flags) {
    int tid = threadIdx.x;
    if (flags[1]) {
        const unsigned short* w = (const unsigned short*)W1;
        for (int idx = tid; idx < 128 * 64; idx += 256) {
            int k = idx >> 6, n = idx & 63;
            wT[n * 128 + k] = w[idx];
        }
    } else {
        const float* w = (const float*)W1;
        for (int idx = tid; idx < 128 * 64; idx += 256) {
            int k = idx >> 6, n = idx & 63;
            float v = w[idx];
            unsigned short h = f2bf(v);
            wTh[n * 128 + k] = h;
            wTl[n * 128 + k] = f2bf(v - bf2f(h));
        }
    }
}

// Per-block LDS histogram over B coarse buckets (dst>>9); hist[bucket][block].
__launch_bounds__(256)
__global__ void k_hist(const void* e, int* __restrict__ histT, const int* flags,
                       int E, int B, int HB) {
    __shared__ int hist[1024];
    int tid = threadIdx.x;
    int is64 = flags[0];
    for (int f = tid; f < B; f += 256) hist[f] = 0;
    __syncthreads();
    int base = blockIdx.x * 4096;
    #pragma unroll
    for (int k = 0; k < 16; ++k) {
        int i = base + k * 256 + tid;
        if (i < E) {
            int d = edgeIdx(e, (long long)E + i, is64);
            atomicAdd(&hist[d >> 9], 1);   // LDS atomic
        }
    }
    __syncthreads();
    for (int f = tid; f < B; f += 256)
        histT[(long long)f * HB + blockIdx.x] = hist[f];
}

// Exclusive scan over M = B*HB ints, level A.
__global__ void k_scanA(int* __restrict__ data, int* __restrict__ partial, int M) {
    __shared__ int s[256];
    int tid = threadIdx.x;
    int i = blockIdx.x * 256 + tid;
    int v = (i < M) ? data[i] : 0;
    s[tid] = v; __syncthreads();
    for (int off = 1; off < 256; off <<= 1) {
        int t = (tid >= off) ? s[tid - off] : 0;
        __syncthreads(); s[tid] += t; __syncthreads();
    }
    if (i < M) data[i] = s[tid] - v;
    if (tid == 255) partial[blockIdx.x] = s[255];
}

// Level B: in-place exclusive scan of nP partials (nP <= 8192).
__global__ void k_scanB(int* __restrict__ partial, int nP) {
    __shared__ int s[1024];
    int tid = threadIdx.x;
    int C = (nP + 1023) >> 10;
    int base = tid * C;
    int v[8]; int tot = 0;
    for (int j = 0; j < C; ++j) { v[j] = (base + j < nP) ? partial[base + j] : 0; tot += v[j]; }
    s[tid] = tot; __syncthreads();
    for (int off = 1; off < 1024; off <<= 1) {
        int t = (tid >= off) ? s[tid - off] : 0;
        __syncthreads(); s[tid] += t; __syncthreads();
    }
    int run = s[tid] - tot;
    for (int j = 0; j < C; ++j) { if (base + j < nP) { int tmp = v[j]; partial[base + j] = run; run += tmp; } }
}

// Level C: add block bases; extract bucketStart.
__global__ void k_scanC(int* __restrict__ data, const int* __restrict__ partial,
                        int* __restrict__ bucketStart, int M, int HB, int B, int E) {
    int f = blockIdx.x * 256 + threadIdx.x;
    if (f < M) {
        int val = data[f] + partial[f >> 8];
        data[f] = val;
        int q = f / HB;
        if (f - q * HB == 0) bucketStart[q] = val;
    }
    if (f == 0) bucketStart[B] = E;
}

// Partition: pos = scanned[bucket][block] + LDS-atomic rank.
// part[pos] = src | (dstLocal << 17)   (requires N <= 2^17).
__launch_bounds__(256)
__global__ void k_part(const void* e, const int* __restrict__ histT,
                       int* __restrict__ part, const int* flags,
                       int E, int B, int HB) {
    __shared__ int lcur[1024];
    int tid = threadIdx.x;
    int is64 = flags[0];
    for (int f = tid; f < B; f += 256)
        lcur[f] = histT[(long long)f * HB + blockIdx.x];
    __syncthreads();
    int base = blockIdx.x * 4096;
    #pragma unroll
    for (int k = 0; k < 16; ++k) {
        int i = base + k * 256 + tid;
        if (i < E) {
            int s = edgeIdx(e, i, is64);
            int d = edgeIdx(e, (long long)E + i, is64);
            int pos = atomicAdd(&lcur[d >> 9], 1);   // LDS atomic
            part[pos] = s | ((d & 511) << 17);
        }
    }
}

// Block-per-bucket second sort (512 nodes/bucket).
__launch_bounds__(512)
__global__ void k_sort2(const int* __restrict__ part, const int* __restrict__ bucketStart,
                        int* __restrict__ srcSorted, int* __restrict__ start,
                        float* __restrict__ dinv, int N, int B) {
    __shared__ int cnt[512];
    __shared__ int s[512];
    __shared__ int cur[512];
    int tid = threadIdx.x, b = blockIdx.x;
    cnt[tid] = 0;
    __syncthreads();
    int lo = bucketStart[b], hi = bucketStart[b + 1];
    for (int idx = lo + tid; idx < hi; idx += 512)
        atomicAdd(&cnt[(part[idx] >> 17) & 511], 1);
    __syncthreads();
    int v = cnt[tid];
    s[tid] = v; __syncthreads();
    for (int off = 1; off < 512; off <<= 1) {
        int t = (tid >= off) ? s[tid - off] : 0;
        __syncthreads(); s[tid] += t; __syncthreads();
    }
    int base_ = lo + s[tid] - v;   // exclusive-scan position
    cur[tid] = base_;
    int node = b * 512 + tid;
    if (node < N) {
        start[node] = base_;
        dinv[node] = rsqrtf((float)(v + 1));  // +1 self-loop
    }
    if (b == 0 && tid == 0) start[N] = bucketStart[B];  // = E
    __syncthreads();
    for (int idx = lo + tid; idx < hi; idx += 512) {
        int pw = part[idx];
        int pos = atomicAdd(&cur[(pw >> 17) & 511], 1);  // LDS atomic w/ return
        srcSorted[pos] = pw & 0x1FFFF;
    }
}

// Merged MFMA GEMM, LDS-free, QUARTERED store layout:
//   hbq[((nt*N + row)*16 + r] = bf16((x@W1)[row][nt*16+r] * dinv[row])
__launch_bounds__(256)
__global__ void k_gemm(const void* x, const unsigned short* __restrict__ wT,
                       const unsigned short* __restrict__ wTh,
                       const unsigned short* __restrict__ wTl,
                       const float* __restrict__ dinv,
                       unsigned short* __restrict__ hbq, const int* flags, int N) {
    int tid = threadIdx.x;
    int lane = tid & 63, wv = tid >> 6;
    int q = lane >> 4, r = lane & 15;
    int gw = blockIdx.x * 4 + wv;
    int nW = gridDim.x * 4;
    int RB = (N + 15) >> 4;
    int isbf = flags[1];
    for (int rb = gw; rb < RB; rb += nW) {
        int row0 = rb * 16;
        int arow = row0 + r;
        f4_t acc[4];
        #pragma unroll
        for (int nt = 0; nt < 4; ++nt) acc[nt] = (f4_t){0.f, 0.f, 0.f, 0.f};
        if (isbf) {
            const unsigned short* xb = (const unsigned short*)x;
            s8_t a[4];
            #pragma unroll
            for (int kk = 0; kk < 4; ++kk)
                a[kk] = (arow < N)
                    ? *(const s8_t*)&xb[(long long)arow * 128 + kk * 32 + q * 8]
                    : (s8_t)(short)0;
            #pragma unroll
            for (int nt = 0; nt < 4; ++nt) {
                #pragma unroll
                for (int kk = 0; kk < 4; ++kk) {
                    s8_t b = *(const s8_t*)&wT[(nt * 16 + r) * 128 + kk * 32 + q * 8];
                    acc[nt] = __builtin_amdgcn_mfma_f32_16x16x32_bf16(a[kk], b, acc[nt], 0, 0, 0);
                }
            }
        } else {
            const float* xf = (const float*)x;
            s8_t ah[4], al[4];
            #pragma unroll
            for (int kk = 0; kk < 4; ++kk) {
                f4_t x0 = (f4_t){0.f, 0.f, 0.f, 0.f}, x1 = x0;
                if (arow < N) {
                    const float* p = &xf[(long long)arow * 128 + kk * 32 + q * 8];
                    x0 = *(const f4_t*)p;
                    x1 = *(const f4_t*)(p + 4);
                }
                #pragma unroll
                for (int j = 0; j < 4; ++j) {
                    union { float f; unsigned int u; } c0, h0, r0, c1, h1, r1;
                    c0.f = x0[j];
                    h0.u = c0.u & 0xffff0000u;
                    ah[kk][j] = (short)(c0.u >> 16);
                    r0.f = x0[j] - h0.f;
                    al[kk][j] = (short)(r0.u >> 16);
                    c1.f = x1[j];
                    h1.u = c1.u & 0xffff0000u;
                    ah[kk][4 + j] = (short)(c1.u >> 16);
                    r1.f = x1[j] - h1.f;
                    al[kk][4 + j] = (short)(r1.u >> 16);
                }
            }
            #pragma unroll
            for (int nt = 0; nt < 4; ++nt) {
                #pragma unroll
                for (int kk = 0; kk < 4; ++kk) {
                    s8_t bh = *(const s8_t*)&wTh[(nt * 16 + r) * 128 + kk * 32 + q * 8];
                    s8_t bl = *(const s8_t*)&wTl[(nt * 16 + r) * 128 + kk * 32 + q * 8];
                    acc[nt] = __builtin_amdgcn_mfma_f32_16x16x32_bf16(ah[kk], bh, acc[nt], 0, 0, 0);
                    acc[nt] = __builtin_amdgcn_mfma_f32_16x16x32_bf16(al[kk], bh, acc[nt], 0, 0, 0);
                    acc[nt] = __builtin_amdgcn_mfma_f32_16x16x32_bf16(ah[kk], bl, acc[nt], 0, 0, 0);
                }
            }
        }
        #pragma unroll
        for (int reg = 0; reg < 4; ++reg) {
            int row = row0 + q * 4 + reg;
            if (row < N) {
                float dv = dinv[row];
                #pragma unroll
                for (int nt = 0; nt < 4; ++nt)
                    hbq[((long long)nt * N + row) * 16 + r] = f2bf(acc[nt][reg] * dv);
            }
        }
    }
}

// R17 layer-1 aggregation: quarter-major L2-resident gather, group-per-node.
// Wave = 4 groups of 16 lanes; group g, lane r. Wave owns 16 nodes =
// 4 batches x 4 groups. Pass q: all waves gather only from hbq[q] (3.2MB,
// per-XCD-L2-resident). Per chunk: 16 index loads (64B/group contiguous),
// 16 in-group shuffles, 16 gather instrs IN FLIGHT (4 rows x 32B = 128B
// each). Lane (g,r) accumulates feature q*16+r of node n0+b*4+g directly;
// acc[4][4] statically indexed; no cross-lane reduction in the main loop.
__launch_bounds__(256)
__global__ void k_agg1(const unsigned short* __restrict__ hbq,
                       const float* __restrict__ dinv,
                       const int* __restrict__ start,
                       const int* __restrict__ srcSorted,
                       const void* b1, const void* W2, float* __restrict__ sbuf2,
                       const int* flags, int N) {
    int lane = threadIdx.x & 63;
    int wid = (blockIdx.x * blockDim.x + threadIdx.x) >> 6;
    int g = lane >> 4, r = lane & 15;
    int g16 = g << 4;
    int n0 = wid * 16;
    if (n0 >= N) return;

    // Preload start[n0 .. n0+16] across lanes (clamped; padded nodes -> cnt 0).
    int sl = n0 + lane;
    int startv = start[sl > N ? N : sl];

    // Per-batch (q-invariant) base/cnt for this lane's group-node.
    int baseB[4], cntB[4];
    #pragma unroll
    for (int b = 0; b < 4; ++b) {
        int lo = __shfl(startv, b * 4 + g);
        int hi = __shfl(startv, b * 4 + g + 1);
        baseB[b] = lo;
        cntB[b] = hi - lo;
    }

    float acc[4][4];   // [batch][quarter], feature q*16+r of node n0+b*4+g
    #pragma unroll
    for (int b = 0; b < 4; ++b)
        #pragma unroll
        for (int q = 0; q < 4; ++q) acc[b][q] = 0.f;

    #pragma unroll
    for (int q = 0; q < 4; ++q) {
        const unsigned short* tab = hbq + (long long)q * N * 16;
        #pragma unroll
        for (int b = 0; b < 4; ++b) {
            int cnt = cntB[b], base = baseB[b];
            float a = 0.f;
            for (int c = 0; c < cnt; c += 16) {   // cnt group-uniform
                int t = c + r;
                int sidx = (t < cnt) ? srcSorted[base + t] : 0;
                int e[16];
                #pragma unroll
                for (int t2 = 0; t2 < 16; ++t2) e[t2] = __shfl(sidx, g16 + t2);
                float v[16];
                #pragma unroll
                for (int t2 = 0; t2 < 16; ++t2)
                    v[t2] = bf2f(tab[(long long)e[t2] * 16 + r]);
                #pragma unroll
                for (int t2 = 0; t2 < 16; ++t2)
                    a += (c + t2 < cnt) ? v[t2] : 0.f;
            }
            acc[b][q] += a;
        }
    }

    int isbf = flags[1];
    float b1v[4], w2v[4];
    #pragma unroll
    for (int q = 0; q < 4; ++q) {
        b1v[q] = loadF(b1, q * 16 + r, isbf);
        w2v[q] = loadF(W2, q * 16 + r, isbf);
    }
    #pragma unroll
    for (int b = 0; b < 4; ++b) {
        int node = n0 + b * 4 + g;
        if (node < N) {
            float di = dinv[node];   // group-uniform load (broadcast)
            float p = 0.f;
            #pragma unroll
            for (int q = 0; q < 4; ++q) {
                unsigned short sv = hbq[((long long)q * N + node) * 16 + r];
                float v = (acc[b][q] + bf2f(sv)) * di + b1v[q];
                v = fmaxf(v, 0.f);
                p += v * w2v[q];
            }
            p += __shfl_xor(p, 1); p += __shfl_xor(p, 2);
            p += __shfl_xor(p, 4); p += __shfl_xor(p, 8);
            if (r == 0) sbuf2[node] = p * di;
        }
    }
}

// Layer-2: out[i] = (sum_src sbuf2[src] + sbuf2[i]) * dinv[i] + b2.
__launch_bounds__(256)
__global__ void k_agg2(const float* __restrict__ sbuf2, const float* __restrict__ dinv,
                       const int* __restrict__ start,
                       const int* __restrict__ srcSorted,
                       const void* b2, void* out, const int* flags, int N) {
    int lane = threadIdx.x & 63;
    int node = (blockIdx.x * blockDim.x + threadIdx.x) >> 6;
    if (node >= N) return;
    int isbf = flags[1];
    float di = dinv[node];
    int base = start[node], cnt = start[node + 1] - base;
    float part = 0.f;
    for (int t = lane; t < cnt; t += 64) part += sbuf2[srcSorted[base + t]];
    #pragma unroll
    for (int o = 32; o >= 1; o >>= 1) part += __shfl_xor(part, o);
    if (lane == 0) {
        float o_ = (part + sbuf2[node]) * di + loadF(b2, 0, isbf);
        if (isbf) ((unsigned short*)out)[node] = f2bf(o_);
        else      ((float*)out)[node] = o_;
    }
}

extern "C" void kernel_launch(void* const* d_in, const int* in_sizes, int n_in,
                              void* d_out, int out_size, void* d_ws, size_t ws_size,
                              hipStream_t stream) {
    const void* x  = d_in[0];
    const void* e  = d_in[1];
    const void* W1 = d_in[2];
    const void* b1 = d_in[3];
    const void* W2 = d_in[4];
    const void* b2 = d_in[5];
    int N = in_sizes[0] / 128;     // 100000
    int E = in_sizes[1] / 2;       // 3200000
    int B  = (N + 511) / 512;      // 196 buckets of 512 nodes
    int HB = (E + 4095) / 4096;    // 782 hist blocks
    int M  = B * HB;               // 153,272
    int nP = (M + 255) / 256;      // 599 (<=8192)
    int NB = B * 512;              // 100,352 padded nodes
    int EP = ((E + 255) / 256) * 256;
    int RB = (N + 15) / 16;        // 6250 row-blocks
    int GG = (RB + 3) / 4;         // 1563 blocks: one row-block per wave
    int AW = (RB + 3) / 4;         // agg1: 6250 waves (16 nodes each) -> 1563 blocks

    // Workspace (~27 MB; 40.4 MB proven safe, 52.8 MB crashes):
    int*   wsI         = (int*)d_ws;
    int*   flags       = wsI;                              // 256
    unsigned short* wT  = (unsigned short*)(wsI + 256);    // 8192 ushorts (16KB)
    unsigned short* wTh = (unsigned short*)(wsI + 256 + 4096);  // 8192 ushorts
    unsigned short* wTl = (unsigned short*)(wsI + 256 + 8192);  // 8192 ushorts
    int*   histT       = wsI + 256 + 12288;                // M rounded
    int*   partial     = histT + ((M + 255) / 256) * 256;  // nP rounded
    int*   bucketStart = partial + ((nP + 255) / 256) * 256;  // B+1 -> 1040
    float* dinv        = (float*)(bucketStart + 1040);     // NB
    float* sbuf2       = dinv + NB;                        // NB
    int*   start       = (int*)(sbuf2 + NB);               // NB + 256
    int*   srcSorted   = start + NB + 256;                 // EP
    int*   part        = srcSorted + EP;                   // EP (12.8 MB)
    unsigned short* hbq = (unsigned short*)part;           // 4*N*16 bf16, ALIASES part

    hipLaunchKernelGGL(k_detect, dim3(1), dim3(64), 0, stream, e, x, flags);
    hipLaunchKernelGGL(k_prep_all, dim3(1), dim3(256), 0, stream, W1, wT, wTh, wTl, flags);
    hipLaunchKernelGGL(k_hist, dim3(HB), dim3(256), 0, stream, e, histT, flags, E, B, HB);
    hipLaunchKernelGGL(k_scanA, dim3(nP), dim3(256), 0, stream, histT, partial, M);
    hipLaunchKernelGGL(k_scanB, dim3(1), dim3(1024), 0, stream, partial, nP);
    hipLaunchKernelGGL(k_scanC, dim3(nP), dim3(256), 0, stream,
                       histT, partial, bucketStart, M, HB, B, E);
    hipLaunchKernelGGL(k_part, dim3(HB), dim3(256), 0, stream, e, histT, part, flags, E, B, HB);
    hipLaunchKernelGGL(k_sort2, dim3(B), dim3(512), 0, stream,
                       part, bucketStart, srcSorted, start, dinv, N, B);
    hipLaunchKernelGGL(k_gemm, dim3(GG), dim3(256), 0, stream,
                       x, wT, wTh, wTl, dinv, hbq, flags, N);
    hipLaunchKernelGGL(k_agg1, dim3(AW), dim3(256), 0, stream,
                       hbq, dinv, start, srcSorted, b1, W2, sbuf2, flags, N);
    hipLaunchKernelGGL(k_agg2, dim3((N + 3) / 4), dim3(256), 0, stream,
                       sbuf2, dinv, start, srcSorted, b2, d_out, flags, N);
}

// Round 4
// 381.645 us; speedup vs baseline: 1.3878x; 1.3878x over previous
//
#include <hip/hip_runtime.h>
#include <hip/hip_bf16.h>

// GCN 2-layer on MI355X — global-atomic-free CSR build + register-acc aggregation.
// R5: global atomicAdd walled ~24 ops/ns device-wide -> no global atomics.
// R6: bucketed LDS-atomic aggregation FAILED (no TLP + in-order LDS pipe).
// R7/R8: hist->scan->part->sort2 CSR + wave-per-node register-acc agg.
// R9/R10: MFMA gemm spill-bound at 98us (frag cache > VGPR budget).
// R11: LDS-free MFMA gemm -> gemm off top-5; agg1 89us @ 3.36 TB/s.
// R12: wide-gather agg1 REGRESSED: VMEM index loads entered the gather chain.
// R13: 512-node buckets: -15us on the partition pipeline.
// R14: deeper gather pipeline neutral -> agg1 at the L2-miss path wall.
// R15: harness feeds f32 -> LDS-free MFMA gemm via bf16 hi/lo split. -26us.
// R16: quartered hbq[q][N][16] (3.2MB < 4MB/XCD L2), quarter-major sweep.
//      FETCH 292->128MB (residency PROVEN) but 88->167us: 4-8 loads in
//      flight, node-serial -> latency-bound.
// R17: group-per-node, 16 gathers/chunk. 296us WORSE: batch loop OUTSIDE a
//      dynamic chunk loop -> compiler can't overlap across the dynamic
//      boundary; each chunk = full dependent chain; MLP ~512B/wave.
// R18: loop inversion. Dynamic step loop OUTERMOST (wave-uniform nsteps =
//      ceil(max-degree/16), 6 shfl_xor); inside: straight-line static code:
//      prefetch next idx (off-chain), 64 shuffles + 64 gathers for ALL 4
//      batches (v[4][16] static), 64 unpredicated adds. 8KB in flight/wave
//      (4x the 88us kernel) on an L2-resident slice. Predication removed
//      via ZERO ROW at index N (slices strided N+1, zeroed in k_gemm);
//      invalid slots gather row N -> add 0.

typedef short s8_t __attribute__((ext_vector_type(8)));
typedef float f4_t __attribute__((ext_vector_type(4)));

__device__ __forceinline__ float bf2f(unsigned short u) {
    union { unsigned int u; float f; } c; c.u = ((unsigned int)u) << 16; return c.f;
}
__device__ __forceinline__ unsigned short f2bf(float f) {
    union { float f; unsigned int u; } c; c.f = f;
    unsigned int u = c.u;
    unsigned int r = (u + 0x7fffu + ((u >> 16) & 1u)) >> 16;  // round-nearest-even
    return (unsigned short)r;
}
__device__ __forceinline__ float loadF(const void* p, int i, int isbf) {
    return isbf ? bf2f(((const unsigned short*)p)[i]) : ((const float*)p)[i];
}
__device__ __forceinline__ int edgeIdx(const void* e, long long i, int is64) {
    return is64 ? (int)((const long long*)e)[i] : ((const int*)e)[i];
}

// flags[0] = edge indices are int64; flags[1] = float tensors are bf16
__global__ void k_detect(const void* e, const void* x, int* flags) {
    int lane = threadIdx.x;  // blockDim = 64
    unsigned int ew = ((const unsigned int*)e)[2 * lane + 1];
    unsigned long long nz = __ballot(ew != 0);
    unsigned int xw = ((const unsigned int*)x)[lane];
    unsigned int low = xw & 0xffffu;
    unsigned int e8 = (low >> 7) & 0xffu;
    bool plaus = (low == 0u) || (e8 >= 110u && e8 <= 135u);
    unsigned long long pl = __ballot(plaus);
    if (lane == 0) {
        flags[0] = (nz == 0ull) ? 1 : 0;
        flags[1] = (__popcll(pl) > 32) ? 1 : 0;
    }
}

// Merged weight prep. bf16 mode: wT[n][k] = W1[k][n].
// f32 mode: transposed bf16 hi/lo pair wTh + wTl ~= W1^T (rne split).
__global__ void k_prep_all(const void* W1, unsigned short* __restrict__ wT,
                           unsigned short* __restrict__ wTh,
                           unsigned short* __restrict__ wTl, const int* flags) {
    int tid = threadIdx.x;
    if (flags[1]) {
        const unsigned short* w = (const unsigned short*)W1;
        for (int idx = tid; idx < 128 * 64; idx += 256) {
            int k = idx >> 6, n = idx & 63;
            wT[n * 128 + k] = w[idx];
        }
    } else {
        const float* w = (const float*)W1;
        for (int idx = tid; idx < 128 * 64; idx += 256) {
            int k = idx >> 6, n = idx & 63;
            float v = w[idx];
            unsigned short h = f2bf(v);
            wTh[n * 128 + k] = h;
            wTl[n * 128 + k] = f2bf(v - bf2f(h));
        }
    }
}

// Per-block LDS histogram over B coarse buckets (dst>>9); hist[bucket][block].
__launch_bounds__(256)
__global__ void k_hist(const void* e, int* __restrict__ histT, const int* flags,
                       int E, int B, int HB) {
    __shared__ int hist[1024];
    int tid = threadIdx.x;
    int is64 = flags[0];
    for (int f = tid; f < B; f += 256) hist[f] = 0;
    __syncthreads();
    int base = blockIdx.x * 4096;
    #pragma unroll
    for (int k = 0; k < 16; ++k) {
        int i = base + k * 256 + tid;
        if (i < E) {
            int d = edgeIdx(e, (long long)E + i, is64);
            atomicAdd(&hist[d >> 9], 1);   // LDS atomic
        }
    }
    __syncthreads();
    for (int f = tid; f < B; f += 256)
        histT[(long long)f * HB + blockIdx.x] = hist[f];
}

// Exclusive scan over M = B*HB ints, level A.
__global__ void k_scanA(int* __restrict__ data, int* __restrict__ partial, int M) {
    __shared__ int s[256];
    int tid = threadIdx.x;
    int i = blockIdx.x * 256 + tid;
    int v = (i < M) ? data[i] : 0;
    s[tid] = v; __syncthreads();
    for (int off = 1; off < 256; off <<= 1) {
        int t = (tid >= off) ? s[tid - off] : 0;
        __syncthreads(); s[tid] += t; __syncthreads();
    }
    if (i < M) data[i] = s[tid] - v;
    if (tid == 255) partial[blockIdx.x] = s[255];
}

// Level B: in-place exclusive scan of nP partials (nP <= 8192).
__global__ void k_scanB(int* __restrict__ partial, int nP) {
    __shared__ int s[1024];
    int tid = threadIdx.x;
    int C = (nP + 1023) >> 10;
    int base = tid * C;
    int v[8]; int tot = 0;
    for (int j = 0; j < C; ++j) { v[j] = (base + j < nP) ? partial[base + j] : 0; tot += v[j]; }
    s[tid] = tot; __syncthreads();
    for (int off = 1; off < 1024; off <<= 1) {
        int t = (tid >= off) ? s[tid - off] : 0;
        __syncthreads(); s[tid] += t; __syncthreads();
    }
    int run = s[tid] - tot;
    for (int j = 0; j < C; ++j) { if (base + j < nP) { int tmp = v[j]; partial[base + j] = run; run += tmp; } }
}

// Level C: add block bases; extract bucketStart.
__global__ void k_scanC(int* __restrict__ data, const int* __restrict__ partial,
                        int* __restrict__ bucketStart, int M, int HB, int B, int E) {
    int f = blockIdx.x * 256 + threadIdx.x;
    if (f < M) {
        int val = data[f] + partial[f >> 8];
        data[f] = val;
        int q = f / HB;
        if (f - q * HB == 0) bucketStart[q] = val;
    }
    if (f == 0) bucketStart[B] = E;
}

// Partition: pos = scanned[bucket][block] + LDS-atomic rank.
// part[pos] = src | (dstLocal << 17)   (requires N <= 2^17).
__launch_bounds__(256)
__global__ void k_part(const void* e, const int* __restrict__ histT,
                       int* __restrict__ part, const int* flags,
                       int E, int B, int HB) {
    __shared__ int lcur[1024];
    int tid = threadIdx.x;
    int is64 = flags[0];
    for (int f = tid; f < B; f += 256)
        lcur[f] = histT[(long long)f * HB + blockIdx.x];
    __syncthreads();
    int base = blockIdx.x * 4096;
    #pragma unroll
    for (int k = 0; k < 16; ++k) {
        int i = base + k * 256 + tid;
        if (i < E) {
            int s = edgeIdx(e, i, is64);
            int d = edgeIdx(e, (long long)E + i, is64);
            int pos = atomicAdd(&lcur[d >> 9], 1);   // LDS atomic
            part[pos] = s | ((d & 511) << 17);
        }
    }
}

// Block-per-bucket second sort (512 nodes/bucket).
__launch_bounds__(512)
__global__ void k_sort2(const int* __restrict__ part, const int* __restrict__ bucketStart,
                        int* __restrict__ srcSorted, int* __restrict__ start,
                        float* __restrict__ dinv, int N, int B) {
    __shared__ int cnt[512];
    __shared__ int s[512];
    __shared__ int cur[512];
    int tid = threadIdx.x, b = blockIdx.x;
    cnt[tid] = 0;
    __syncthreads();
    int lo = bucketStart[b], hi = bucketStart[b + 1];
    for (int idx = lo + tid; idx < hi; idx += 512)
        atomicAdd(&cnt[(part[idx] >> 17) & 511], 1);
    __syncthreads();
    int v = cnt[tid];
    s[tid] = v; __syncthreads();
    for (int off = 1; off < 512; off <<= 1) {
        int t = (tid >= off) ? s[tid - off] : 0;
        __syncthreads(); s[tid] += t; __syncthreads();
    }
    int base_ = lo + s[tid] - v;   // exclusive-scan position
    cur[tid] = base_;
    int node = b * 512 + tid;
    if (node < N) {
        start[node] = base_;
        dinv[node] = rsqrtf((float)(v + 1));  // +1 self-loop
    }
    if (b == 0 && tid == 0) start[N] = bucketStart[B];  // = E
    __syncthreads();
    for (int idx = lo + tid; idx < hi; idx += 512) {
        int pw = part[idx];
        int pos = atomicAdd(&cur[(pw >> 17) & 511], 1);  // LDS atomic w/ return
        srcSorted[pos] = pw & 0x1FFFF;
    }
}

// Merged MFMA GEMM, LDS-free, QUARTERED store layout, slices strided N+1:
//   hbq[(nt*(N+1) + row)*16 + r] = bf16((x@W1)[row][nt*16+r] * dinv[row])
// Row N of each slice is the ZERO ROW (gather target for masked edges).
__launch_bounds__(256)
__global__ void k_gemm(const void* x, const unsigned short* __restrict__ wT,
                       const unsigned short* __restrict__ wTh,
                       const unsigned short* __restrict__ wTl,
                       const float* __restrict__ dinv,
                       unsigned short* __restrict__ hbq, const int* flags, int N) {
    int tid = threadIdx.x;
    // zero row N of each slice (agg1's masked-edge target)
    if (blockIdx.x == 0 && tid < 64) {
        int nt = tid >> 4, rr = tid & 15;
        hbq[((long long)nt * (N + 1) + N) * 16 + rr] = 0;
    }
    int lane = tid & 63, wv = tid >> 6;
    int q = lane >> 4, r = lane & 15;
    int gw = blockIdx.x * 4 + wv;
    int nW = gridDim.x * 4;
    int RB = (N + 15) >> 4;
    int isbf = flags[1];
    for (int rb = gw; rb < RB; rb += nW) {
        int row0 = rb * 16;
        int arow = row0 + r;
        f4_t acc[4];
        #pragma unroll
        for (int nt = 0; nt < 4; ++nt) acc[nt] = (f4_t){0.f, 0.f, 0.f, 0.f};
        if (isbf) {
            const unsigned short* xb = (const unsigned short*)x;
            s8_t a[4];
            #pragma unroll
            for (int kk = 0; kk < 4; ++kk)
                a[kk] = (arow < N)
                    ? *(const s8_t*)&xb[(long long)arow * 128 + kk * 32 + q * 8]
                    : (s8_t)(short)0;
            #pragma unroll
            for (int nt = 0; nt < 4; ++nt) {
                #pragma unroll
                for (int kk = 0; kk < 4; ++kk) {
                    s8_t b = *(const s8_t*)&wT[(nt * 16 + r) * 128 + kk * 32 + q * 8];
                    acc[nt] = __builtin_amdgcn_mfma_f32_16x16x32_bf16(a[kk], b, acc[nt], 0, 0, 0);
                }
            }
        } else {
            const float* xf = (const float*)x;
            s8_t ah[4], al[4];
            #pragma unroll
            for (int kk = 0; kk < 4; ++kk) {
                f4_t x0 = (f4_t){0.f, 0.f, 0.f, 0.f}, x1 = x0;
                if (arow < N) {
                    const float* p = &xf[(long long)arow * 128 + kk * 32 + q * 8];
                    x0 = *(const f4_t*)p;
                    x1 = *(const f4_t*)(p + 4);
                }
                #pragma unroll
                for (int j = 0; j < 4; ++j) {
                    union { float f; unsigned int u; } c0, h0, r0, c1, h1, r1;
                    c0.f = x0[j];
                    h0.u = c0.u & 0xffff0000u;
                    ah[kk][j] = (short)(c0.u >> 16);
                    r0.f = x0[j] - h0.f;
                    al[kk][j] = (short)(r0.u >> 16);
                    c1.f = x1[j];
                    h1.u = c1.u & 0xffff0000u;
                    ah[kk][4 + j] = (short)(c1.u >> 16);
                    r1.f = x1[j] - h1.f;
                    al[kk][4 + j] = (short)(r1.u >> 16);
                }
            }
            #pragma unroll
            for (int nt = 0; nt < 4; ++nt) {
                #pragma unroll
                for (int kk = 0; kk < 4; ++kk) {
                    s8_t bh = *(const s8_t*)&wTh[(nt * 16 + r) * 128 + kk * 32 + q * 8];
                    s8_t bl = *(const s8_t*)&wTl[(nt * 16 + r) * 128 + kk * 32 + q * 8];
                    acc[nt] = __builtin_amdgcn_mfma_f32_16x16x32_bf16(ah[kk], bh, acc[nt], 0, 0, 0);
                    acc[nt] = __builtin_amdgcn_mfma_f32_16x16x32_bf16(al[kk], bh, acc[nt], 0, 0, 0);
                    acc[nt] = __builtin_amdgcn_mfma_f32_16x16x32_bf16(ah[kk], bl, acc[nt], 0, 0, 0);
                }
            }
        }
        #pragma unroll
        for (int reg = 0; reg < 4; ++reg) {
            int row = row0 + q * 4 + reg;
            if (row < N) {
                float dv = dinv[row];
                #pragma unroll
                for (int nt = 0; nt < 4; ++nt)
                    hbq[((long long)nt * (N + 1) + row) * 16 + r] = f2bf(acc[nt][reg] * dv);
            }
        }
    }
}

// R18 layer-1 aggregation: quarter-major L2-resident gather, loop-inverted.
// Wave owns 16 nodes (4 batches x 4 groups); lane (g,r). Outer: q (slice).
// Middle: wave-uniform step loop (nsteps = ceil(max-degree/16)). Inner:
// STRAIGHT-LINE static code: prefetch next step's 4 idx words, 64 shuffles
// + 64 gathers (all 4 batches, v[4][16]) -> 8KB in flight/wave, then 64
// unpredicated adds (masked slots gather the zero row N).
__launch_bounds__(256)
__global__ void k_agg1(const unsigned short* __restrict__ hbq,
                       const float* __restrict__ dinv,
                       const int* __restrict__ start,
                       const int* __restrict__ srcSorted,
                       const void* b1, const void* W2, float* __restrict__ sbuf2,
                       const int* flags, int N) {
    int lane = threadIdx.x & 63;
    int wid = (blockIdx.x * blockDim.x + threadIdx.x) >> 6;
    int g = lane >> 4, r = lane & 15;
    int g16 = g << 4;
    int n0 = wid * 16;
    if (n0 >= N) return;

    // start[n0 .. n0+16] in lanes 0..16 (clamped; padded nodes -> cnt 0).
    int sl = n0 + lane;
    int startv = start[sl > N ? N : sl];

    int baseB[4], cntB[4];
    #pragma unroll
    for (int b = 0; b < 4; ++b) {
        int lo = __shfl(startv, b * 4 + g);
        int hi = __shfl(startv, b * 4 + g + 1);
        baseB[b] = lo;
        cntB[b] = hi - lo;
    }

    // wave-uniform step count: max degree over the wave's 16 nodes
    int cmax = cntB[0] > cntB[1] ? cntB[0] : cntB[1];
    cmax = cmax > cntB[2] ? cmax : cntB[2];
    cmax = cmax > cntB[3] ? cmax : cntB[3];
    #pragma unroll
    for (int o = 32; o >= 1; o >>= 1) {
        int t = __shfl_xor(cmax, o);
        cmax = cmax > t ? cmax : t;
    }
    int nsteps = (cmax + 15) >> 4;

    float acc[4][4];   // [batch][quarter]: feature q*16+r of node n0+b*4+g
    #pragma unroll
    for (int b = 0; b < 4; ++b)
        #pragma unroll
        for (int q = 0; q < 4; ++q) acc[b][q] = 0.f;

    long long stride = (long long)(N + 1) * 16;
    #pragma unroll
    for (int q = 0; q < 4; ++q) {
        const unsigned short* tab = hbq + q * stride;
        // prefetch step 0 indices (masked slots -> zero row N)
        int cur[4];
        #pragma unroll
        for (int b = 0; b < 4; ++b) {
            int ok = r < cntB[b];
            int ld = srcSorted[baseB[b] + (ok ? r : 0)];
            cur[b] = ok ? ld : N;
        }
        for (int s = 0; s < nsteps; ++s) {
            // prefetch next step's indices (off the critical chain)
            int nxt[4];
            int t1 = (s + 1) * 16 + r;
            #pragma unroll
            for (int b = 0; b < 4; ++b) {
                int ok = t1 < cntB[b];
                int ld = srcSorted[baseB[b] + (ok ? t1 : 0)];
                nxt[b] = ok ? ld : N;
            }
            // 64 shuffles + 64 gathers, all batches, straight-line
            float v[4][16];
            #pragma unroll
            for (int b = 0; b < 4; ++b) {
                #pragma unroll
                for (int t2 = 0; t2 < 16; ++t2) {
                    int ee = __shfl(cur[b], g16 + t2);
                    v[b][t2] = bf2f(tab[(ee << 4) | r]);
                }
            }
            // 64 unpredicated adds (zero row handles masking)
            #pragma unroll
            for (int b = 0; b < 4; ++b) {
                float a0 = 0.f, a1 = 0.f;
                #pragma unroll
                for (int t2 = 0; t2 < 8; ++t2) {
                    a0 += v[b][2 * t2];
                    a1 += v[b][2 * t2 + 1];
                }
                acc[b][q] += a0 + a1;
            }
            #pragma unroll
            for (int b = 0; b < 4; ++b) cur[b] = nxt[b];
        }
    }

    int isbf = flags[1];
    float b1v[4], w2v[4];
    #pragma unroll
    for (int q = 0; q < 4; ++q) {
        b1v[q] = loadF(b1, q * 16 + r, isbf);
        w2v[q] = loadF(W2, q * 16 + r, isbf);
    }
    #pragma unroll
    for (int b = 0; b < 4; ++b) {
        int node = n0 + b * 4 + g;
        if (node < N) {
            float di = dinv[node];   // group-uniform load (broadcast)
            float p = 0.f;
            #pragma unroll
            for (int q = 0; q < 4; ++q) {
                unsigned short sv = hbq[q * stride + (long long)node * 16 + r];
                float v = (acc[b][q] + bf2f(sv)) * di + b1v[q];
                v = fmaxf(v, 0.f);
                p += v * w2v[q];
            }
            p += __shfl_xor(p, 1); p += __shfl_xor(p, 2);
            p += __shfl_xor(p, 4); p += __shfl_xor(p, 8);
            if (r == 0) sbuf2[node] = p * di;
        }
    }
}

// Layer-2: out[i] = (sum_src sbuf2[src] + sbuf2[i]) * dinv[i] + b2.
__launch_bounds__(256)
__global__ void k_agg2(const float* __restrict__ sbuf2, const float* __restrict__ dinv,
                       const int* __restrict__ start,
                       const int* __restrict__ srcSorted,
                       const void* b2, void* out, const int* flags, int N) {
    int lane = threadIdx.x & 63;
    int node = (blockIdx.x * blockDim.x + threadIdx.x) >> 6;
    if (node >= N) return;
    int isbf = flags[1];
    float di = dinv[node];
    int base = start[node], cnt = start[node + 1] - base;
    float part = 0.f;
    for (int t = lane; t < cnt; t += 64) part += sbuf2[srcSorted[base + t]];
    #pragma unroll
    for (int o = 32; o >= 1; o >>= 1) part += __shfl_xor(part, o);
    if (lane == 0) {
        float o_ = (part + sbuf2[node]) * di + loadF(b2, 0, isbf);
        if (isbf) ((unsigned short*)out)[node] = f2bf(o_);
        else      ((float*)out)[node] = o_;
    }
}

extern "C" void kernel_launch(void* const* d_in, const int* in_sizes, int n_in,
                              void* d_out, int out_size, void* d_ws, size_t ws_size,
                              hipStream_t stream) {
    const void* x  = d_in[0];
    const void* e  = d_in[1];
    const void* W1 = d_in[2];
    const void* b1 = d_in[3];
    const void* W2 = d_in[4];
    const void* b2 = d_in[5];
    int N = in_sizes[0] / 128;     // 100000
    int E = in_sizes[1] / 2;       // 3200000
    int B  = (N + 511) / 512;      // 196 buckets of 512 nodes
    int HB = (E + 4095) / 4096;    // 782 hist blocks
    int M  = B * HB;               // 153,272
    int nP = (M + 255) / 256;      // 599 (<=8192)
    int NB = B * 512;              // 100,352 padded nodes
    int EP = ((E + 255) / 256) * 256;
    int RB = (N + 15) / 16;        // 6250 row-blocks
    int GG = (RB + 3) / 4;         // 1563 blocks: one row-block per wave
    int AW = (RB + 3) / 4;         // agg1: 6250 waves (16 nodes each) -> 1563 blocks

    // Workspace (~27.5 MB; 40.4 MB proven safe, 52.8 MB crashes):
    int*   wsI         = (int*)d_ws;
    int*   flags       = wsI;                              // 256
    unsigned short* wT  = (unsigned short*)(wsI + 256);    // 8192 ushorts (16KB)
    unsigned short* wTh = (unsigned short*)(wsI + 256 + 4096);  // 8192 ushorts
    unsigned short* wTl = (unsigned short*)(wsI + 256 + 8192);  // 8192 ushorts
    int*   histT       = wsI + 256 + 12288;                // M rounded
    int*   partial     = histT + ((M + 255) / 256) * 256;  // nP rounded
    int*   bucketStart = partial + ((nP + 255) / 256) * 256;  // B+1 -> 1040
    float* dinv        = (float*)(bucketStart + 1040);     // NB
    float* sbuf2       = dinv + NB;                        // NB
    int*   start       = (int*)(sbuf2 + NB);               // NB + 256
    int*   srcSorted   = start + NB + 256;                 // EP
    int*   part        = srcSorted + EP;                   // EP (12.8 MB)
    unsigned short* hbq = (unsigned short*)part;           // 4*(N+1)*16 bf16, ALIASES
                                                           // part (+128B tail into ws slack)

    hipLaunchKernelGGL(k_detect, dim3(1), dim3(64), 0, stream, e, x, flags);
    hipLaunchKernelGGL(k_prep_all, dim3(1), dim3(256), 0, stream, W1, wT, wTh, wTl, flags);
    hipLaunchKernelGGL(k_hist, dim3(HB), dim3(256), 0, stream, e, histT, flags, E, B, HB);
    hipLaunchKernelGGL(k_scanA, dim3(nP), dim3(256), 0, stream, histT, partial, M);
    hipLaunchKernelGGL(k_scanB, dim3(1), dim3(1024), 0, stream, partial, nP);
    hipLaunchKernelGGL(k_scanC, dim3(nP), dim3(256), 0, stream,
                       histT, partial, bucketStart, M, HB, B, E);
    hipLaunchKernelGGL(k_part, dim3(HB), dim3(256), 0, stream, e, histT, part, flags, E, B, HB);
    hipLaunchKernelGGL(k_sort2, dim3(B), dim3(512), 0, stream,
                       part, bucketStart, srcSorted, start, dinv, N, B);
    hipLaunchKernelGGL(k_gemm, dim3(GG), dim3(256), 0, stream,
                       x, wT, wTh, wTl, dinv, hbq, flags, N);
    hipLaunchKernelGGL(k_agg1, dim3(AW), dim3(256), 0, stream,
                       hbq, dinv, start, srcSorted, b1, W2, sbuf2, flags, N);
    hipLaunchKernelGGL(k_agg2, dim3((N + 3) / 4), dim3(256), 0, stream,
                       sbuf2, dinv, start, srcSorted, b2, d_out, flags, N);
}

// Round 5
// 336.727 us; speedup vs baseline: 1.5730x; 1.1334x over previous
//
#include <hip/hip_runtime.h>
#include <hip/hip_bf16.h>

// GCN 2-layer on MI355X — global-atomic-free CSR build + register-acc aggregation.
// R5: global atomicAdd walled ~24 ops/ns device-wide -> no global atomics.
// R6: bucketed LDS-atomic aggregation FAILED (no TLP + in-order LDS pipe).
// R7/R8: hist->scan->part->sort2 CSR + wave-per-node register-acc agg.
// R9/R10: MFMA gemm spill-bound at 98us (frag cache > VGPR budget).
// R11: LDS-free MFMA gemm -> gemm off top-5; agg1 89us @ 3.36 TB/s.
// R12: wide-gather agg1 REGRESSED: VMEM index loads entered the gather chain.
// R13: 512-node buckets: -15us on the partition pipeline.
// R14: deeper gather pipeline neutral -> agg1 at the L2-miss path wall.
// R15: harness feeds f32 -> LDS-free MFMA gemm via bf16 hi/lo split. -26us.
// R16: quartered hbq[q][N+1][16] slices (3.2MB < 4MB/XCD L2), quarter-major
//      sweep. FETCH 292->128MB (residency PROVEN) but latency-bound: 167us.
// R17: group-per-node: 296us (batch loop outside dynamic loop = serial).
// R18: loop inversion, 2KB in flight/wave: FETCH blew up to 343MB. Waves
//      desync across q-passes (3 generations, imbalance tail) -> each XCD
//      had 2-3 slices live -> L2 thrash. Phase sync is luck, not structure.
// R19: quarter-per-KERNEL. 4 dispatches of k_agg1q(q); within a dispatch
//      every resident wave touches ONLY slice q -> per-XCD residency is
//      guaranteed by the kernel boundary. Epilogue separable per quarter
//      (relu is per-feature): pass q accumulates p_q into sbuf2 (pass 0
//      writes, 3 scales by di). Inner = R18's straight-line form, single
//      dynamic loop: 1 idx load + prefetch, 16 shuffles, 16 gathers in
//      flight (2KB/wave), 16 unpredicated adds (zero-row masking).

typedef short s8_t __attribute__((ext_vector_type(8)));
typedef float f4_t __attribute__((ext_vector_type(4)));

__device__ __forceinline__ float bf2f(unsigned short u) {
    union { unsigned int u; float f; } c; c.u = ((unsigned int)u) << 16; return c.f;
}
__device__ __forceinline__ unsigned short f2bf(float f) {
    union { float f; unsigned int u; } c; c.f = f;
    unsigned int u = c.u;
    unsigned int r = (u + 0x7fffu + ((u >> 16) & 1u)) >> 16;  // round-nearest-even
    return (unsigned short)r;
}
__device__ __forceinline__ float loadF(const void* p, int i, int isbf) {
    return isbf ? bf2f(((const unsigned short*)p)[i]) : ((const float*)p)[i];
}
__device__ __forceinline__ int edgeIdx(const void* e, long long i, int is64) {
    return is64 ? (int)((const long long*)e)[i] : ((const int*)e)[i];
}

// flags[0] = edge indices are int64; flags[1] = float tensors are bf16
__global__ void k_detect(const void* e, const void* x, int* flags) {
    int lane = threadIdx.x;  // blockDim = 64
    unsigned int ew = ((const unsigned int*)e)[2 * lane + 1];
    unsigned long long nz = __ballot(ew != 0);
    unsigned int xw = ((const unsigned int*)x)[lane];
    unsigned int low = xw & 0xffffu;
    unsigned int e8 = (low >> 7) & 0xffu;
    bool plaus = (low == 0u) || (e8 >= 110u && e8 <= 135u);
    unsigned long long pl = __ballot(plaus);
    if (lane == 0) {
        flags[0] = (nz == 0ull) ? 1 : 0;
        flags[1] = (__popcll(pl) > 32) ? 1 : 0;
    }
}

// Merged weight prep. bf16 mode: wT[n][k] = W1[k][n].
// f32 mode: transposed bf16 hi/lo pair wTh + wTl ~= W1^T (rne split).
__global__ void k_prep_all(const void* W1, unsigned short* __restrict__ wT,
                           unsigned short* __restrict__ wTh,
                           unsigned short* __restrict__ wTl, const int* flags) {
    int tid = threadIdx.x;
    if (flags[1]) {
        const unsigned short* w = (const unsigned short*)W1;
        for (int idx = tid; idx < 128 * 64; idx += 256) {
            int k = idx >> 6, n = idx & 63;
            wT[n * 128 + k] = w[idx];
        }
    } else {
        const float* w = (const float*)W1;
        for (int idx = tid; idx < 128 * 64; idx += 256) {
            int k = idx >> 6, n = idx & 63;
            float v = w[idx];
            unsigned short h = f2bf(v);
            wTh[n * 128 + k] = h;
            wTl[n * 128 + k] = f2bf(v - bf2f(h));
        }
    }
}

// Per-block LDS histogram over B coarse buckets (dst>>9); hist[bucket][block].
__launch_bounds__(256)
__global__ void k_hist(const void* e, int* __restrict__ histT, const int* flags,
                       int E, int B, int HB) {
    __shared__ int hist[1024];
    int tid = threadIdx.x;
    int is64 = flags[0];
    for (int f = tid; f < B; f += 256) hist[f] = 0;
    __syncthreads();
    int base = blockIdx.x * 4096;
    #pragma unroll
    for (int k = 0; k < 16; ++k) {
        int i = base + k * 256 + tid;
        if (i < E) {
            int d = edgeIdx(e, (long long)E + i, is64);
            atomicAdd(&hist[d >> 9], 1);   // LDS atomic
        }
    }
    __syncthreads();
    for (int f = tid; f < B; f += 256)
        histT[(long long)f * HB + blockIdx.x] = hist[f];
}

// Exclusive scan over M = B*HB ints, level A.
__global__ void k_scanA(int* __restrict__ data, int* __restrict__ partial, int M) {
    __shared__ int s[256];
    int tid = threadIdx.x;
    int i = blockIdx.x * 256 + tid;
    int v = (i < M) ? data[i] : 0;
    s[tid] = v; __syncthreads();
    for (int off = 1; off < 256; off <<= 1) {
        int t = (tid >= off) ? s[tid - off] : 0;
        __syncthreads(); s[tid] += t; __syncthreads();
    }
    if (i < M) data[i] = s[tid] - v;
    if (tid == 255) partial[blockIdx.x] = s[255];
}

// Level B: in-place exclusive scan of nP partials (nP <= 8192).
__global__ void k_scanB(int* __restrict__ partial, int nP) {
    __shared__ int s[1024];
    int tid = threadIdx.x;
    int C = (nP + 1023) >> 10;
    int base = tid * C;
    int v[8]; int tot = 0;
    for (int j = 0; j < C; ++j) { v[j] = (base + j < nP) ? partial[base + j] : 0; tot += v[j]; }
    s[tid] = tot; __syncthreads();
    for (int off = 1; off < 1024; off <<= 1) {
        int t = (tid >= off) ? s[tid - off] : 0;
        __syncthreads(); s[tid] += t; __syncthreads();
    }
    int run = s[tid] - tot;
    for (int j = 0; j < C; ++j) { if (base + j < nP) { int tmp = v[j]; partial[base + j] = run; run += tmp; } }
}

// Level C: add block bases; extract bucketStart.
__global__ void k_scanC(int* __restrict__ data, const int* __restrict__ partial,
                        int* __restrict__ bucketStart, int M, int HB, int B, int E) {
    int f = blockIdx.x * 256 + threadIdx.x;
    if (f < M) {
        int val = data[f] + partial[f >> 8];
        data[f] = val;
        int q = f / HB;
        if (f - q * HB == 0) bucketStart[q] = val;
    }
    if (f == 0) bucketStart[B] = E;
}

// Partition: pos = scanned[bucket][block] + LDS-atomic rank.
// part[pos] = src | (dstLocal << 17)   (requires N <= 2^17).
__launch_bounds__(256)
__global__ void k_part(const void* e, const int* __restrict__ histT,
                       int* __restrict__ part, const int* flags,
                       int E, int B, int HB) {
    __shared__ int lcur[1024];
    int tid = threadIdx.x;
    int is64 = flags[0];
    for (int f = tid; f < B; f += 256)
        lcur[f] = histT[(long long)f * HB + blockIdx.x];
    __syncthreads();
    int base = blockIdx.x * 4096;
    #pragma unroll
    for (int k = 0; k < 16; ++k) {
        int i = base + k * 256 + tid;
        if (i < E) {
            int s = edgeIdx(e, i, is64);
            int d = edgeIdx(e, (long long)E + i, is64);
            int pos = atomicAdd(&lcur[d >> 9], 1);   // LDS atomic
            part[pos] = s | ((d & 511) << 17);
        }
    }
}

// Block-per-bucket second sort (512 nodes/bucket).
__launch_bounds__(512)
__global__ void k_sort2(const int* __restrict__ part, const int* __restrict__ bucketStart,
                        int* __restrict__ srcSorted, int* __restrict__ start,
                        float* __restrict__ dinv, int N, int B) {
    __shared__ int cnt[512];
    __shared__ int s[512];
    __shared__ int cur[512];
    int tid = threadIdx.x, b = blockIdx.x;
    cnt[tid] = 0;
    __syncthreads();
    int lo = bucketStart[b], hi = bucketStart[b + 1];
    for (int idx = lo + tid; idx < hi; idx += 512)
        atomicAdd(&cnt[(part[idx] >> 17) & 511], 1);
    __syncthreads();
    int v = cnt[tid];
    s[tid] = v; __syncthreads();
    for (int off = 1; off < 512; off <<= 1) {
        int t = (tid >= off) ? s[tid - off] : 0;
        __syncthreads(); s[tid] += t; __syncthreads();
    }
    int base_ = lo + s[tid] - v;   // exclusive-scan position
    cur[tid] = base_;
    int node = b * 512 + tid;
    if (node < N) {
        start[node] = base_;
        dinv[node] = rsqrtf((float)(v + 1));  // +1 self-loop
    }
    if (b == 0 && tid == 0) start[N] = bucketStart[B];  // = E
    __syncthreads();
    for (int idx = lo + tid; idx < hi; idx += 512) {
        int pw = part[idx];
        int pos = atomicAdd(&cur[(pw >> 17) & 511], 1);  // LDS atomic w/ return
        srcSorted[pos] = pw & 0x1FFFF;
    }
}

// Merged MFMA GEMM, LDS-free, QUARTERED store layout, slices strided N+1:
//   hbq[(nt*(N+1) + row)*16 + r] = bf16((x@W1)[row][nt*16+r] * dinv[row])
// Row N of each slice is the ZERO ROW (gather target for masked edges).
__launch_bounds__(256)
__global__ void k_gemm(const void* x, const unsigned short* __restrict__ wT,
                       const unsigned short* __restrict__ wTh,
                       const unsigned short* __restrict__ wTl,
                       const float* __restrict__ dinv,
                       unsigned short* __restrict__ hbq, const int* flags, int N) {
    int tid = threadIdx.x;
    // zero row N of each slice (agg1's masked-edge target)
    if (blockIdx.x == 0 && tid < 64) {
        int nt = tid >> 4, rr = tid & 15;
        hbq[((long long)nt * (N + 1) + N) * 16 + rr] = 0;
    }
    int lane = tid & 63, wv = tid >> 6;
    int q = lane >> 4, r = lane & 15;
    int gw = blockIdx.x * 4 + wv;
    int nW = gridDim.x * 4;
    int RB = (N + 15) >> 4;
    int isbf = flags[1];
    for (int rb = gw; rb < RB; rb += nW) {
        int row0 = rb * 16;
        int arow = row0 + r;
        f4_t acc[4];
        #pragma unroll
        for (int nt = 0; nt < 4; ++nt) acc[nt] = (f4_t){0.f, 0.f, 0.f, 0.f};
        if (isbf) {
            const unsigned short* xb = (const unsigned short*)x;
            s8_t a[4];
            #pragma unroll
            for (int kk = 0; kk < 4; ++kk)
                a[kk] = (arow < N)
                    ? *(const s8_t*)&xb[(long long)arow * 128 + kk * 32 + q * 8]
                    : (s8_t)(short)0;
            #pragma unroll
            for (int nt = 0; nt < 4; ++nt) {
                #pragma unroll
                for (int kk = 0; kk < 4; ++kk) {
                    s8_t b = *(const s8_t*)&wT[(nt * 16 + r) * 128 + kk * 32 + q * 8];
                    acc[nt] = __builtin_amdgcn_mfma_f32_16x16x32_bf16(a[kk], b, acc[nt], 0, 0, 0);
                }
            }
        } else {
            const float* xf = (const float*)x;
            s8_t ah[4], al[4];
            #pragma unroll
            for (int kk = 0; kk < 4; ++kk) {
                f4_t x0 = (f4_t){0.f, 0.f, 0.f, 0.f}, x1 = x0;
                if (arow < N) {
                    const float* p = &xf[(long long)arow * 128 + kk * 32 + q * 8];
                    x0 = *(const f4_t*)p;
                    x1 = *(const f4_t*)(p + 4);
                }
                #pragma unroll
                for (int j = 0; j < 4; ++j) {
                    union { float f; unsigned int u; } c0, h0, r0, c1, h1, r1;
                    c0.f = x0[j];
                    h0.u = c0.u & 0xffff0000u;
                    ah[kk][j] = (short)(c0.u >> 16);
                    r0.f = x0[j] - h0.f;
                    al[kk][j] = (short)(r0.u >> 16);
                    c1.f = x1[j];
                    h1.u = c1.u & 0xffff0000u;
                    ah[kk][4 + j] = (short)(c1.u >> 16);
                    r1.f = x1[j] - h1.f;
                    al[kk][4 + j] = (short)(r1.u >> 16);
                }
            }
            #pragma unroll
            for (int nt = 0; nt < 4; ++nt) {
                #pragma unroll
                for (int kk = 0; kk < 4; ++kk) {
                    s8_t bh = *(const s8_t*)&wTh[(nt * 16 + r) * 128 + kk * 32 + q * 8];
                    s8_t bl = *(const s8_t*)&wTl[(nt * 16 + r) * 128 + kk * 32 + q * 8];
                    acc[nt] = __builtin_amdgcn_mfma_f32_16x16x32_bf16(ah[kk], bh, acc[nt], 0, 0, 0);
                    acc[nt] = __builtin_amdgcn_mfma_f32_16x16x32_bf16(al[kk], bh, acc[nt], 0, 0, 0);
                    acc[nt] = __builtin_amdgcn_mfma_f32_16x16x32_bf16(ah[kk], bl, acc[nt], 0, 0, 0);
                }
            }
        }
        #pragma unroll
        for (int reg = 0; reg < 4; ++reg) {
            int row = row0 + q * 4 + reg;
            if (row < N) {
                float dv = dinv[row];
                #pragma unroll
                for (int nt = 0; nt < 4; ++nt)
                    hbq[((long long)nt * (N + 1) + row) * 16 + r] = f2bf(acc[nt][reg] * dv);
            }
        }
    }
}

// R19 layer-1 aggregation, ONE QUARTER PER DISPATCH (q is a kernel arg).
// Within this dispatch every wave gathers ONLY from slice q (3.2MB) ->
// per-XCD L2 residency guaranteed by the kernel boundary. Wave = 4 nodes
// (one per 16-lane group); lane (g,r) accumulates feature q*16+r of node
// n0+g. Single wave-uniform step loop; per step: 1 coalesced idx load
// (prefetched), 16 shuffles, 16 gather instrs in flight (2KB/wave), 16
// unpredicated adds (masked slots gather zero row N). Epilogue: partial
// dot p_q accumulated into sbuf2 (pass 0 writes, pass 3 scales by di).
__launch_bounds__(256)
__global__ void k_agg1q(const unsigned short* __restrict__ hbq,
                        const float* __restrict__ dinv,
                        const int* __restrict__ start,
                        const int* __restrict__ srcSorted,
                        const void* b1, const void* W2, float* __restrict__ sbuf2,
                        const int* flags, int N, int q) {
    int lane = threadIdx.x & 63;
    int wid = (blockIdx.x * blockDim.x + threadIdx.x) >> 6;
    int g = lane >> 4, r = lane & 15;
    int g16 = g << 4;
    int n0 = wid * 4;           // wave owns nodes n0 .. n0+3 (node n0+g per group)
    if (n0 >= N) return;

    // start[n0 .. n0+4] via lanes 0..4 (clamped)
    int sl = n0 + lane;
    int startv = start[sl > N ? N : sl];
    int base = __shfl(startv, g);
    int cnt  = __shfl(startv, g + 1) - base;

    // wave-uniform nsteps = ceil(max-over-groups(cnt)/16)
    int cmax = cnt;
    int tt = __shfl_xor(cmax, 16); cmax = cmax > tt ? cmax : tt;
    tt = __shfl_xor(cmax, 32);     cmax = cmax > tt ? cmax : tt;
    int nsteps = (cmax + 15) >> 4;

    long long stride = (long long)(N + 1) * 16;
    const unsigned short* tab = hbq + q * stride;

    float acc = 0.f;
    // prefetch step 0 indices (masked slots -> zero row N)
    int ok0 = r < cnt;
    int ld0 = srcSorted[base + (ok0 ? r : 0)];
    int cur = ok0 ? ld0 : N;

    for (int s = 0; s < nsteps; ++s) {
        // prefetch next step's indices (off the critical chain)
        int t1 = (s + 1) * 16 + r;
        int ok = t1 < cnt;
        int ld = srcSorted[base + (ok ? t1 : 0)];
        int nxt = ok ? ld : N;
        // 16 shuffles + 16 gathers, straight-line, all in flight
        float v[16];
        #pragma unroll
        for (int t2 = 0; t2 < 16; ++t2) {
            int ee = __shfl(cur, g16 + t2);
            v[t2] = bf2f(tab[(ee << 4) | r]);
        }
        float a0 = 0.f, a1 = 0.f;
        #pragma unroll
        for (int t2 = 0; t2 < 8; ++t2) {
            a0 += v[2 * t2];
            a1 += v[2 * t2 + 1];
        }
        acc += a0 + a1;
        cur = nxt;
    }

    int node = n0 + g;
    if (node < N) {
        int isbf = flags[1];
        float b1v = loadF(b1, q * 16 + r, isbf);
        float w2v = loadF(W2, q * 16 + r, isbf);
        float di = dinv[node];     // group-uniform (broadcast)
        unsigned short sv = tab[(node << 4) | r];   // self row lives in slice q
        float vv = (acc + bf2f(sv)) * di + b1v;
        vv = fmaxf(vv, 0.f);
        float p = vv * w2v;
        p += __shfl_xor(p, 1); p += __shfl_xor(p, 2);
        p += __shfl_xor(p, 4); p += __shfl_xor(p, 8);
        if (r == 0) {
            if (q == 0)      sbuf2[node] = p;
            else if (q < 3)  sbuf2[node] += p;
            else             sbuf2[node] = (sbuf2[node] + p) * di;
        }
    }
}

// Layer-2: out[i] = (sum_src sbuf2[src] + sbuf2[i]) * dinv[i] + b2.
__launch_bounds__(256)
__global__ void k_agg2(const float* __restrict__ sbuf2, const float* __restrict__ dinv,
                       const int* __restrict__ start,
                       const int* __restrict__ srcSorted,
                       const void* b2, void* out, const int* flags, int N) {
    int lane = threadIdx.x & 63;
    int node = (blockIdx.x * blockDim.x + threadIdx.x) >> 6;
    if (node >= N) return;
    int isbf = flags[1];
    float di = dinv[node];
    int base = start[node], cnt = start[node + 1] - base;
    float part = 0.f;
    for (int t = lane; t < cnt; t += 64) part += sbuf2[srcSorted[base + t]];
    #pragma unroll
    for (int o = 32; o >= 1; o >>= 1) part += __shfl_xor(part, o);
    if (lane == 0) {
        float o_ = (part + sbuf2[node]) * di + loadF(b2, 0, isbf);
        if (isbf) ((unsigned short*)out)[node] = f2bf(o_);
        else      ((float*)out)[node] = o_;
    }
}

extern "C" void kernel_launch(void* const* d_in, const int* in_sizes, int n_in,
                              void* d_out, int out_size, void* d_ws, size_t ws_size,
                              hipStream_t stream) {
    const void* x  = d_in[0];
    const void* e  = d_in[1];
    const void* W1 = d_in[2];
    const void* b1 = d_in[3];
    const void* W2 = d_in[4];
    const void* b2 = d_in[5];
    int N = in_sizes[0] / 128;     // 100000
    int E = in_sizes[1] / 2;       // 3200000
    int B  = (N + 511) / 512;      // 196 buckets of 512 nodes
    int HB = (E + 4095) / 4096;    // 782 hist blocks
    int M  = B * HB;               // 153,272
    int nP = (M + 255) / 256;      // 599 (<=8192)
    int NB = B * 512;              // 100,352 padded nodes
    int EP = ((E + 255) / 256) * 256;
    int RB = (N + 15) / 16;        // 6250 row-blocks
    int GG = (RB + 3) / 4;         // 1563 blocks: one row-block per wave
    int AQ = (N + 15) / 16;        // agg1q: 16 nodes/block (4 waves x 4 nodes)

    // Workspace (~27.5 MB; 40.4 MB proven safe, 52.8 MB crashes):
    int*   wsI         = (int*)d_ws;
    int*   flags       = wsI;                              // 256
    unsigned short* wT  = (unsigned short*)(wsI + 256);    // 8192 ushorts (16KB)
    unsigned short* wTh = (unsigned short*)(wsI + 256 + 4096);  // 8192 ushorts
    unsigned short* wTl = (unsigned short*)(wsI + 256 + 8192);  // 8192 ushorts
    int*   histT       = wsI + 256 + 12288;                // M rounded
    int*   partial     = histT + ((M + 255) / 256) * 256;  // nP rounded
    int*   bucketStart = partial + ((nP + 255) / 256) * 256;  // B+1 -> 1040
    float* dinv        = (float*)(bucketStart + 1040);     // NB
    float* sbuf2       = dinv + NB;                        // NB
    int*   start       = (int*)(sbuf2 + NB);               // NB + 256
    int*   srcSorted   = start + NB + 256;                 // EP
    int*   part        = srcSorted + EP;                   // EP (12.8 MB)
    unsigned short* hbq = (unsigned short*)part;           // 4*(N+1)*16 bf16, ALIASES
                                                           // part (+128B tail into ws slack)

    hipLaunchKernelGGL(k_detect, dim3(1), dim3(64), 0, stream, e, x, flags);
    hipLaunchKernelGGL(k_prep_all, dim3(1), dim3(256), 0, stream, W1, wT, wTh, wTl, flags);
    hipLaunchKernelGGL(k_hist, dim3(HB), dim3(256), 0, stream, e, histT, flags, E, B, HB);
    hipLaunchKernelGGL(k_scanA, dim3(nP), dim3(256), 0, stream, histT, partial, M);
    hipLaunchKernelGGL(k_scanB, dim3(1), dim3(1024), 0, stream, partial, nP);
    hipLaunchKernelGGL(k_scanC, dim3(nP), dim3(256), 0, stream,
                       histT, partial, bucketStart, M, HB, B, E);
    hipLaunchKernelGGL(k_part, dim3(HB), dim3(256), 0, stream, e, histT, part, flags, E, B, HB);
    hipLaunchKernelGGL(k_sort2, dim3(B), dim3(512), 0, stream,
                       part, bucketStart, srcSorted, start, dinv, N, B);
    hipLaunchKernelGGL(k_gemm, dim3(GG), dim3(256), 0, stream,
                       x, wT, wTh, wTl, dinv, hbq, flags, N);
    for (int q = 0; q < 4; ++q)
        hipLaunchKernelGGL(k_agg1q, dim3(AQ), dim3(256), 0, stream,
                           hbq, dinv, start, srcSorted, b1, W2, sbuf2, flags, N, q);
    hipLaunchKernelGGL(k_agg2, dim3((N + 3) / 4), dim3(256), 0, stream,
                       sbuf2, dinv, start, srcSorted, b2, d_out, flags, N);
}